// Round 20
// baseline (394.417 us; speedup 1.0000x reference)
//
#include <hip/hip_runtime.h>
#include <hip/hip_bf16.h>
#include <math.h>

#define B_ 8
#define N_ 900
#define D_ 256
#define S_ 21760
#define H_ 8
#define DH 32
#define FF_ 2048
#define NROWS (B_*N_)   // 7200

typedef __attribute__((ext_vector_type(8))) short bf16x8;
typedef __attribute__((ext_vector_type(4))) float f32x4;

union BU { bf16x8 v; short s[8]; unsigned long long u[2]; };

static __device__ inline short f2bf_s(float x) {
  __hip_bfloat16 h = __float2bfloat16(x);
  return *reinterpret_cast<short*>(&h);
}

__device__ __forceinline__ void gload_lds16(const float* g, float* lds) {
  __builtin_amdgcn_global_load_lds(
      (const __attribute__((address_space(1))) void*)g,
      (__attribute__((address_space(3))) void*)lds, 16, 0, 0);
}

// ---------------------------------------------------------------- RoPE (bf16 out)
__global__ __launch_bounds__(128) void rope_kernel(
    const float* __restrict__ tgt, const float* __restrict__ qpos,
    const float* __restrict__ boxes, __hip_bfloat16* __restrict__ out)
{
  int row = blockIdx.x;
  int tid = threadIdx.x;
  const float* x = tgt  + (size_t)row * D_;
  const float* p = qpos + (size_t)row * D_;
  float a0 = x[2*tid]   + p[2*tid];
  float a1 = x[2*tid+1] + p[2*tid+1];
  float o0 = a0, o1 = a1;
  if (tid < 126) {
    int band = tid / 42;
    int fi   = tid - band * 42;
    float freq = powf(10000.0f, -(float)fi / 42.0f);
    float cx = boxes[(size_t)row*4 + 0];
    float cy = boxes[(size_t)row*4 + 1];
    float v  = (band == 0) ? cx : (band == 1 ? cy : cx * cy);
    if (band == 2) freq *= 0.1f;
    float ang = v * freq;
    float c = cosf(ang), s = sinf(ang);
    o0 = a0 * c - a1 * s;
    o1 = a1 * c + a0 * s;
  }
  short2 sv = make_short2(f2bf_s(o0), f2bf_s(o1));
  *(short2*)&out[(size_t)row*D_ + 2*tid] = sv;
}

// ---------------------------------------------------------------- weight transpose+convert
// Layout (elems): qk 0 (wq@0, wk@65536), wv 131072, sa 196608,
// off 262144, aw 327680, val 360448, co 425984, ff1 491520, ff2 1015808.
__global__ __launch_bounds__(256) void wtrans_kernel(
    const float* __restrict__ wq, const float* __restrict__ wk,
    const float* __restrict__ wv, const float* __restrict__ sa_wo,
    const float* __restrict__ offw, const float* __restrict__ valw,
    const float* __restrict__ cow, const float* __restrict__ aww,
    const float* __restrict__ ff1w, const float* __restrict__ ff2w,
    short* __restrict__ Wt)
{
  int bid = blockIdx.x;
  const float* W; short* out; int K, N, tile;
  if (bid < 448) {
    int wi = bid >> 6; tile = bid & 63; K = 256; N = 256;
    const float* tab[7] = {wq, wk, wv, sa_wo, offw, valw, cow};
    const int   off[7]  = {0, 65536, 131072, 196608, 262144, 360448, 425984};
    W = tab[wi]; out = Wt + off[wi];
  } else if (bid < 480) {
    tile = bid - 448; K = 256; N = 128; W = aww; out = Wt + 327680;
  } else if (bid < 992) {
    tile = bid - 480; K = 256; N = 2048; W = ff1w; out = Wt + 491520;
  } else {
    tile = bid - 992; K = 2048; N = 256; W = ff2w; out = Wt + 1015808;
  }
  int ntn = N >> 5;
  int tk = tile / ntn, tn = tile - tk * ntn;
  __shared__ float t[32][33];
  int c = threadIdx.x & 31, rr = threadIdx.x >> 5;
  #pragma unroll
  for (int i = 0; i < 4; ++i)
    t[rr + i*8][c] = W[(size_t)(tk*32 + rr + i*8) * N + tn*32 + c];
  __syncthreads();
  #pragma unroll
  for (int i = 0; i < 4; ++i)
    out[(size_t)(tn*32 + rr + i*8) * K + tk*32 + c] = f2bf_s(t[c][rr + i*8]);
}

// ---------------------------------------------------------------- MFMA GEMM (K-strip)
// OUTMODE: 0 fp32 [M][N]; 1 bf16 [M][N]; 2 bf16 attn-V transpose;
//          3 dual bf16; 4 dual fp32; 5 fused residual-add + LayerNorm.
// AUX (OUTMODE 5 only): 0 none; 1 also write bf16 (LN_out + A2p row) to Cp2;
//                       2 also write bf16 LN_out to Cp2.
template<int BM, int KK, bool ABF16, bool A2ADD, bool RELU, int OUTMODE, int AUX>
__global__ __launch_bounds__(256) void mgemm_kernel(
    const void* __restrict__ Ap, const float* __restrict__ A2p,
    const short* __restrict__ Wt,
    const float* __restrict__ bias, const float* __restrict__ bias2,
    void* __restrict__ Cp, void* __restrict__ Cp2, int M, int N,
    const float* __restrict__ Xres, const float* __restrict__ lng,
    const float* __restrict__ lnb)
{
  constexpr int MS = BM / 16;
  constexpr bool SWAP = (OUTMODE != 2);
  __shared__ short As[BM * 256];
  int tid = threadIdx.x;
  int w = tid >> 6, lane = tid & 63;
  int g = lane >> 4, r = lane & 15;
  int m0 = blockIdx.x * BM;
  int nw = blockIdx.y * 256 + w * 64;
  bool active = nw < N;

  f32x4 acc[MS][4];
  #pragma unroll
  for (int i = 0; i < MS; ++i)
    #pragma unroll
    for (int j = 0; j < 4; ++j) acc[i][j] = (f32x4){0.f,0.f,0.f,0.f};

  for (int kb = 0; kb < KK; kb += 256) {
    if (KK > 256 && kb) __syncthreads();
    #pragma unroll
    for (int i = 0; i < BM/8; ++i) {
      int u = i*256 + tid;
      int row = u >> 5, c8 = u & 31;
      BU pk;
      if (ABF16) {
        pk.v = *(const bf16x8*)((const short*)Ap + (size_t)(m0+row)*KK + kb + c8*8);
      } else {
        const float* ap = (const float*)Ap + (size_t)(m0+row)*KK + kb + c8*8;
        float4 a0 = *(const float4*)ap;
        float4 a1 = *(const float4*)(ap + 4);
        if (A2ADD) {
          const float* a2 = A2p + (size_t)(m0+row)*KK + kb + c8*8;
          float4 b0 = *(const float4*)a2;
          float4 b1 = *(const float4*)(a2 + 4);
          a0.x += b0.x; a0.y += b0.y; a0.z += b0.z; a0.w += b0.w;
          a1.x += b1.x; a1.y += b1.y; a1.z += b1.z; a1.w += b1.w;
        }
        pk.s[0]=f2bf_s(a0.x); pk.s[1]=f2bf_s(a0.y); pk.s[2]=f2bf_s(a0.z); pk.s[3]=f2bf_s(a0.w);
        pk.s[4]=f2bf_s(a1.x); pk.s[5]=f2bf_s(a1.y); pk.s[6]=f2bf_s(a1.z); pk.s[7]=f2bf_s(a1.w);
      }
      int col = (c8*8) ^ ((row & 7) << 3);
      *(bf16x8*)&As[row*256 + col] = pk.v;
    }
    __syncthreads();
    if (active) {
      #pragma unroll
      for (int kk = 0; kk < 8; ++kk) {
        BU bfr[4];
        #pragma unroll
        for (int ns = 0; ns < 4; ++ns) {
          const short* wp = Wt + (size_t)(nw + ns*16 + r)*KK + kb + kk*32;
          bfr[ns].u[0] = *(const unsigned long long*)(wp + 4*g);
          bfr[ns].u[1] = *(const unsigned long long*)(wp + 16 + 4*g);
        }
        #pragma unroll
        for (int ms = 0; ms < MS; ++ms) {
          int row = ms*16 + r;
          int c0 = (kk*32 + g*4)      ^ ((r & 7) << 3);
          int c1 = (kk*32 + 16 + g*4) ^ ((r & 7) << 3);
          BU af;
          af.u[0] = *(const unsigned long long*)&As[row*256 + c0];
          af.u[1] = *(const unsigned long long*)&As[row*256 + c1];
          #pragma unroll
          for (int ns = 0; ns < 4; ++ns) {
            if (SWAP)
              acc[ms][ns] = __builtin_amdgcn_mfma_f32_16x16x32_bf16(
                  bfr[ns].v, af.v, acc[ms][ns], 0, 0, 0);
            else
              acc[ms][ns] = __builtin_amdgcn_mfma_f32_16x16x32_bf16(
                  af.v, bfr[ns].v, acc[ms][ns], 0, 0, 0);
          }
        }
      }
    }
  }

  if (OUTMODE == 5) {
    float vv[MS][16];
    float ps[MS], pq[MS];
    #pragma unroll
    for (int ms = 0; ms < MS; ++ms) {
      ps[ms] = 0.f; pq[ms] = 0.f;
      int m = m0 + ms*16 + r;
      #pragma unroll
      for (int ns = 0; ns < 4; ++ns) {
        int n0 = nw + ns*16 + g*4;
        float4 b4 = *(const float4*)&bias[n0];
        float4 x4 = *(const float4*)&Xres[(size_t)m*256 + n0];
        #pragma unroll
        for (int j = 0; j < 4; ++j) {
          float v = acc[ms][ns][j] + ((const float*)&b4)[j] + ((const float*)&x4)[j];
          vv[ms][ns*4 + j] = v;
          ps[ms] += v; pq[ms] += v*v;
        }
      }
      ps[ms] += __shfl_xor(ps[ms], 16); ps[ms] += __shfl_xor(ps[ms], 32);
      pq[ms] += __shfl_xor(pq[ms], 16); pq[ms] += __shfl_xor(pq[ms], 32);
    }
    __syncthreads();
    float* red = (float*)As;
    if (g == 0) {
      #pragma unroll
      for (int ms = 0; ms < MS; ++ms) {
        red[(ms*16 + r)*8 + w]     = ps[ms];
        red[(ms*16 + r)*8 + 4 + w] = pq[ms];
      }
    }
    __syncthreads();
    #pragma unroll
    for (int ms = 0; ms < MS; ++ms) {
      int rowi = ms*16 + r;
      float ts = red[rowi*8+0]+red[rowi*8+1]+red[rowi*8+2]+red[rowi*8+3];
      float tq = red[rowi*8+4]+red[rowi*8+5]+red[rowi*8+6]+red[rowi*8+7];
      float mu = ts * (1.0f/256.0f);
      float var = tq * (1.0f/256.0f) - mu*mu;
      float rs = rsqrtf(fmaxf(var, 0.f) + 1e-5f);
      int m = m0 + ms*16 + r;
      #pragma unroll
      for (int ns = 0; ns < 4; ++ns) {
        int n0 = nw + ns*16 + g*4;
        float4 g4 = *(const float4*)&lng[n0];
        float4 be = *(const float4*)&lnb[n0];
        float4 ov;
        ov.x = (vv[ms][ns*4+0] - mu)*rs*g4.x + be.x;
        ov.y = (vv[ms][ns*4+1] - mu)*rs*g4.y + be.y;
        ov.z = (vv[ms][ns*4+2] - mu)*rs*g4.z + be.z;
        ov.w = (vv[ms][ns*4+3] - mu)*rs*g4.w + be.w;
        *(float4*)&((float*)Cp)[(size_t)m*256 + n0] = ov;
        if (AUX == 1) {
          float4 q4 = *(const float4*)&A2p[(size_t)m*256 + n0];
          short4 sv = make_short4(
              f2bf_s(ov.x + q4.x), f2bf_s(ov.y + q4.y),
              f2bf_s(ov.z + q4.z), f2bf_s(ov.w + q4.w));
          *(short4*)&((short*)Cp2)[(size_t)m*256 + n0] = sv;
        } else if (AUX == 2) {
          short4 sv = make_short4(
              f2bf_s(ov.x), f2bf_s(ov.y), f2bf_s(ov.z), f2bf_s(ov.w));
          *(short4*)&((short*)Cp2)[(size_t)m*256 + n0] = sv;
        }
      }
    }
    return;
  }

  if (!active) return;

  #pragma unroll
  for (int ms = 0; ms < MS; ++ms) {
    #pragma unroll
    for (int ns = 0; ns < 4; ++ns) {
      if (SWAP) {
        int n0 = nw + ns*16 + g*4;
        int m  = m0 + ms*16 + r;
        float4 b4;
        if (OUTMODE == 3 || OUTMODE == 4)
          b4 = (n0 < 256) ? *(const float4*)&bias[n0]
                          : *(const float4*)&bias2[n0 - 256];
        else
          b4 = *(const float4*)&bias[n0];
        float v0 = acc[ms][ns][0] + b4.x;
        float v1 = acc[ms][ns][1] + b4.y;
        float v2 = acc[ms][ns][2] + b4.z;
        float v3 = acc[ms][ns][3] + b4.w;
        if (RELU) {
          v0 = fmaxf(v0, 0.f); v1 = fmaxf(v1, 0.f);
          v2 = fmaxf(v2, 0.f); v3 = fmaxf(v3, 0.f);
        }
        if (OUTMODE == 0) {
          *(float4*)&((float*)Cp)[(size_t)m*N + n0] = make_float4(v0,v1,v2,v3);
        } else if (OUTMODE == 1) {
          short4 sv = make_short4(f2bf_s(v0), f2bf_s(v1), f2bf_s(v2), f2bf_s(v3));
          *(short4*)&((short*)Cp)[(size_t)m*N + n0] = sv;
        } else if (OUTMODE == 3) {
          short4 sv = make_short4(f2bf_s(v0), f2bf_s(v1), f2bf_s(v2), f2bf_s(v3));
          if (n0 < 256) *(short4*)&((short*)Cp )[(size_t)m*256 + n0]       = sv;
          else          *(short4*)&((short*)Cp2)[(size_t)m*256 + (n0-256)] = sv;
        } else {  // OUTMODE 4
          float4 fv = make_float4(v0,v1,v2,v3);
          if (n0 < 256) *(float4*)&((float*)Cp )[(size_t)m*256 + n0]       = fv;
          else          *(float4*)&((float*)Cp2)[(size_t)m*128 + (n0-256)] = fv;
        }
      } else {  // OUTMODE 2: attn-V transpose
        int n = nw + ns*16 + r;
        float bsc = bias[n];
        int hh = n >> 5, dd = n & 31;
        int mb = m0 + ms*16 + g*4;
        short4 sv = make_short4(
            f2bf_s(acc[ms][ns][0] + bsc), f2bf_s(acc[ms][ns][1] + bsc),
            f2bf_s(acc[ms][ns][2] + bsc), f2bf_s(acc[ms][ns][3] + bsc));
        int bb = mb / N_, bbe = (mb + 3) / N_;
        if (bb == bbe) {
          int nn = mb - bb * N_;
          *(short4*)&((short*)Cp)[((size_t)((bb*H_ + hh)*DH + dd))*N_ + nn] = sv;
        } else {
          const short* sp = (const short*)&sv;
          #pragma unroll
          for (int j = 0; j < 4; ++j) {
            int m = mb + j;
            int b2 = m / N_, nn = m - b2 * N_;
            ((short*)Cp)[((size_t)((b2*H_ + hh)*DH + dd))*N_ + nn] = sp[j];
          }
        }
      }
    }
  }
}

// ---------------------------------------------------------------- attn wave body (no LDS, no barriers)
__device__ __forceinline__ void attn_wave_body(
    int wid, int lane,
    const __hip_bfloat16* __restrict__ Q,
    const __hip_bfloat16* __restrict__ K,
    const __hip_bfloat16* __restrict__ Vt,
    __hip_bfloat16* __restrict__ O)
{
  const int NQT = 29;
  int qt = wid % NQT, bh = wid / NQT;
  int b = bh >> 3, h = bh & 7;
  int g = lane >> 4, r = lane & 15;
  int q0 = qt * 32;
  const float scale = 0.17677669529663687f;

  BU qf[2];
  #pragma unroll
  for (int qq = 0; qq < 2; ++qq) {
    int qrow = min(q0 + qq*16 + r, N_ - 1);
    const __hip_bfloat16* qp = Q + ((size_t)(b*N_ + qrow))*D_ + h*DH;
    qf[qq].u[0] = *(const unsigned long long*)(qp + 4*g);
    qf[qq].u[1] = *(const unsigned long long*)(qp + 16 + 4*g);
  }

  f32x4 oaccA[2], oaccB[2];
  #pragma unroll
  for (int qq = 0; qq < 2; ++qq) {
    oaccA[qq] = (f32x4){0.f,0.f,0.f,0.f};
    oaccB[qq] = (f32x4){0.f,0.f,0.f,0.f};
  }
  float m0v = -1e30f, m1v = -1e30f, l0v = 0.f, l1v = 0.f;
  const f32x4 zero = {0.f,0.f,0.f,0.f};

  const __hip_bfloat16* vbase0 = Vt + (size_t)(bh*DH + r) * N_;
  const __hip_bfloat16* vbase1 = Vt + (size_t)(bh*DH + 16 + r) * N_;

  for (int kt = 0; kt < N_; kt += 32) {
    BU kf0, kf1;
    {
      int kr0 = min(kt + r, N_ - 1);
      int kr1 = min(kt + 16 + r, N_ - 1);
      const __hip_bfloat16* kp0 = K + ((size_t)(b*N_ + kr0))*D_ + h*DH;
      const __hip_bfloat16* kp1 = K + ((size_t)(b*N_ + kr1))*D_ + h*DH;
      kf0.u[0] = *(const unsigned long long*)(kp0 + 4*g);
      kf0.u[1] = *(const unsigned long long*)(kp0 + 16 + 4*g);
      kf1.u[0] = *(const unsigned long long*)(kp1 + 4*g);
      kf1.u[1] = *(const unsigned long long*)(kp1 + 16 + 4*g);
    }
    BU vf0, vf1;
    vf0.u[0] = *(const unsigned long long*)(vbase0 + kt + 4*g);
    vf0.u[1] = *(const unsigned long long*)(vbase0 + kt + 16 + 4*g);
    vf1.u[0] = *(const unsigned long long*)(vbase1 + kt + 4*g);
    vf1.u[1] = *(const unsigned long long*)(vbase1 + kt + 16 + 4*g);

    #pragma unroll
    for (int qq = 0; qq < 2; ++qq) {
      f32x4 s0 = __builtin_amdgcn_mfma_f32_16x16x32_bf16(kf0.v, qf[qq].v, zero, 0, 0, 0);
      f32x4 s1 = __builtin_amdgcn_mfma_f32_16x16x32_bf16(kf1.v, qf[qq].v, zero, 0, 0, 0);
      float m = qq ? m1v : m0v;
      float lv = qq ? l1v : l0v;

      float sc[8];
      #pragma unroll
      for (int j = 0; j < 4; ++j) {
        sc[j]   = (kt + 4*g + j      < N_) ? s0[j] * scale : -1e30f;
        sc[4+j] = (kt + 16 + 4*g + j < N_) ? s1[j] * scale : -1e30f;
      }
      float mx = sc[0];
      #pragma unroll
      for (int j = 1; j < 8; ++j) mx = fmaxf(mx, sc[j]);
      mx = fmaxf(mx, __shfl_xor(mx, 16));
      mx = fmaxf(mx, __shfl_xor(mx, 32));

      float mnew = fmaxf(m, mx);
      float corr = __expf(m - mnew);
      float p[8], ps = 0.f;
      #pragma unroll
      for (int j = 0; j < 8; ++j) { p[j] = __expf(sc[j] - mnew); ps += p[j]; }
      ps += __shfl_xor(ps, 16);
      ps += __shfl_xor(ps, 32);
      lv = lv * corr + ps;
      if (qq) { m1v = mnew; l1v = lv; } else { m0v = mnew; l0v = lv; }
      #pragma unroll
      for (int j = 0; j < 4; ++j) { oaccA[qq][j] *= corr; oaccB[qq][j] *= corr; }

      BU pf;
      #pragma unroll
      for (int j = 0; j < 8; ++j) pf.s[j] = f2bf_s(p[j]);

      oaccA[qq] = __builtin_amdgcn_mfma_f32_16x16x32_bf16(vf0.v, pf.v, oaccA[qq], 0, 0, 0);
      oaccB[qq] = __builtin_amdgcn_mfma_f32_16x16x32_bf16(vf1.v, pf.v, oaccB[qq], 0, 0, 0);
    }
  }

  #pragma unroll
  for (int qq = 0; qq < 2; ++qq) {
    int qrow = q0 + qq*16 + r;
    if (qrow < N_) {
      float inv = 1.0f / (qq ? l1v : l0v);
      short* op = (short*)(O + ((size_t)(b*N_ + qrow))*D_ + h*DH);
      short4 sA = make_short4(
          f2bf_s(oaccA[qq][0]*inv), f2bf_s(oaccA[qq][1]*inv),
          f2bf_s(oaccA[qq][2]*inv), f2bf_s(oaccA[qq][3]*inv));
      short4 sB = make_short4(
          f2bf_s(oaccB[qq][0]*inv), f2bf_s(oaccB[qq][1]*inv),
          f2bf_s(oaccB[qq][2]*inv), f2bf_s(oaccB[qq][3]*inv));
      *(short4*)&op[4*g]      = sA;
      *(short4*)&op[16 + 4*g] = sB;
    }
  }
}

// ---------------------------------------------------------------- fused value-GEMM + attention
// Blocks 0..1087: vgemm (8 waves x 32 cols, W register-resident, 2 chunks
// per barrier, vmcnt(4)). Blocks 1088..1319: 8 independent attn wave-units
// each (attn body has no LDS/barriers; vgemm barriers are block-local).
__global__ __launch_bounds__(512) void vgemm_attn_kernel(
    const float* __restrict__ Ap, const short* __restrict__ Wt,
    const float* __restrict__ bias, short* __restrict__ Cp,
    const __hip_bfloat16* __restrict__ Q, const __hip_bfloat16* __restrict__ K,
    const __hip_bfloat16* __restrict__ Vt, __hip_bfloat16* __restrict__ O)
{
  __shared__ float buf[8][1024];
  __shared__ float dump[1024];
  int tid = threadIdx.x;
  int w = tid >> 6, l = tid & 63;

  if (blockIdx.x >= 1088) {
    int unit = (blockIdx.x - 1088) * 8 + w;   // 0..1855
    attn_wave_body(unit, l, Q, K, Vt, O);
    return;
  }

  int g = l >> 4, r = l & 15;
  int nw = w * 32;

  BU wreg[2][8];
  #pragma unroll
  for (int ns = 0; ns < 2; ++ns) {
    const short* wp = Wt + (size_t)(nw + ns*16 + r) * 256;
    #pragma unroll
    for (int kk = 0; kk < 8; ++kk) {
      wreg[ns][kk].u[0] = *(const unsigned long long*)(wp + kk*32 + 4*g);
      wreg[ns][kk].u[1] = *(const unsigned long long*)(wp + kk*32 + 16 + 4*g);
    }
  }
  float4 bs4[2];
  #pragma unroll
  for (int ns = 0; ns < 2; ++ns) bs4[ns] = *(const float4*)&bias[nw + ns*16 + g*4];

  bool stager = (w < 4);
  int srow = (w & 3)*8 + (l >> 3);
  int schunk = (l & 7) ^ (srow & 7);
  const float* gbase = Ap + ((size_t)blockIdx.x*160 + srow) * 256 + schunk*4;

  if (stager) {
    #pragma unroll
    for (int t = 0; t < 4; ++t)
      gload_lds16(gbase + (t>>3)*8192 + (t&7)*32, &buf[t][(w & 3)*256]);
  }

  f32x4 acc[2][2];
  #pragma unroll
  for (int i = 0; i < 2; ++i)
    #pragma unroll
    for (int j = 0; j < 2; ++j) acc[i][j] = (f32x4){0.f,0.f,0.f,0.f};

  int bb = blockIdx.x / 136;
  int pixblk = (blockIdx.x % 136) * 160;

  for (int s = 0; s < 5; ++s) {
    #pragma unroll
    for (int cp = 0; cp < 4; ++cp) {
      int c = cp*2;
      int t = s*8 + c;
      if (stager) {
        int tn0 = t + 4, tn1 = t + 5;
        if (tn0 < 40) gload_lds16(gbase + (tn0>>3)*8192 + (tn0&7)*32,
                                  &buf[(c+4)&7][(w & 3)*256]);
        else          gload_lds16(gbase, &dump[(w & 3)*256]);
        if (tn1 < 40) gload_lds16(gbase + (tn1>>3)*8192 + (tn1&7)*32,
                                  &buf[(c+5)&7][(w & 3)*256]);
        else          gload_lds16(gbase, &dump[(w & 3)*256]);
        asm volatile("s_waitcnt vmcnt(4)" ::: "memory");
      }
      __builtin_amdgcn_s_barrier();
      #pragma unroll
      for (int cc = 0; cc < 2; ++cc) {
        int ci = c + cc;
        const float* bp = &buf[ci][0];
        #pragma unroll
        for (int ms = 0; ms < 2; ++ms) {
          int row = ms*16 + r;
          const float* rp = bp + row*32;
          float4 f0 = *(const float4*)&rp[((g    ) ^ (row & 7)) * 4];
          float4 f1 = *(const float4*)&rp[((g + 4) ^ (row & 7)) * 4];
          BU af;
          af.s[0]=f2bf_s(f0.x); af.s[1]=f2bf_s(f0.y); af.s[2]=f2bf_s(f0.z); af.s[3]=f2bf_s(f0.w);
          af.s[4]=f2bf_s(f1.x); af.s[5]=f2bf_s(f1.y); af.s[6]=f2bf_s(f1.z); af.s[7]=f2bf_s(f1.w);
          #pragma unroll
          for (int ns = 0; ns < 2; ++ns)
            acc[ms][ns] = __builtin_amdgcn_mfma_f32_16x16x32_bf16(
                wreg[ns][ci].v, af.v, acc[ms][ns], 0, 0, 0);
        }
      }
    }
    int pix0 = pixblk + s*32;
    #pragma unroll
    for (int ms = 0; ms < 2; ++ms) {
      #pragma unroll
      for (int ns = 0; ns < 2; ++ns) {
        int pix = pix0 + ms*16 + r;
        int n0  = nw + ns*16 + g*4;
        int hh = n0 >> 5, dd = n0 & 31;
        short4 sv = make_short4(
            f2bf_s(acc[ms][ns][0] + bs4[ns].x),
            f2bf_s(acc[ms][ns][1] + bs4[ns].y),
            f2bf_s(acc[ms][ns][2] + bs4[ns].z),
            f2bf_s(acc[ms][ns][3] + bs4[ns].w));
        *(short4*)&Cp[((size_t)(bb*H_ + hh)*S_ + pix)*32 + dd] = sv;
        acc[ms][ns] = (f32x4){0.f,0.f,0.f,0.f};
      }
    }
  }
}

// ---------------------------------------------------------------- deformable sampling (4 rows/block, d-quad gathers, bf16 out)
// V layout: [b][h][pix][32]  (pixel stride 64 B)
__global__ __launch_bounds__(256) void sample4_kernel(
    const __hip_bfloat16* __restrict__ V, const float* __restrict__ offp,
    const float* __restrict__ awl, const float* __restrict__ refp,
    short* __restrict__ out)
{
  int tid = threadIdx.x;
  int q = tid >> 6, t = tid & 63;
  int row = blockIdx.x * 4 + q;
  int b = row / N_;
  __shared__ float s_aw[4][128];
  __shared__ float s_loc[4][256];
  #pragma unroll
  for (int i = 0; i < 2; ++i)
    s_aw[q][t + i*64] = awl[(size_t)row*128 + t + i*64];
  {
    const float norms[4] = {128.f, 64.f, 32.f, 16.f};
    #pragma unroll
    for (int i = 0; i < 4; ++i) {
      int e = t + i*64;
      int rem = e & 31, li = rem >> 3, ax = rem & 1;
      s_loc[q][e] = refp[((size_t)row*4 + li)*2 + ax]
                  + offp[(size_t)row*256 + e] / norms[li];
    }
  }
  __syncthreads();
  if (t < 8) {
    float mx = -1e30f;
    for (int j = 0; j < 16; ++j) mx = fmaxf(mx, s_aw[q][t*16+j]);
    float sum = 0.f;
    for (int j = 0; j < 16; ++j) sum += __expf(s_aw[q][t*16+j] - mx);
    float inv = 1.0f / sum;
    for (int j = 0; j < 16; ++j)
      s_aw[q][t*16+j] = __expf(s_aw[q][t*16+j] - mx) * inv;
  }
  __syncthreads();
  int h = t >> 3, dq = t & 7;
  const int dims[4]   = {128, 64, 32, 16};
  const int starts[4] = {0, 16384, 20480, 21504};
  const __hip_bfloat16* Vb = V + ((size_t)(b*H_ + h) * S_) * 32 + dq*4;
  float a0 = 0.f, a1 = 0.f, a2 = 0.f, a3 = 0.f;
  #pragma unroll
  for (int l = 0; l < 4; ++l) {
    int Wl = dims[l], st = starts[l];
    #pragma unroll
    for (int p = 0; p < 4; ++p) {
      float lx = s_loc[q][h*32 + l*8 + p*2 + 0];
      float ly = s_loc[q][h*32 + l*8 + p*2 + 1];
      float x = lx * Wl - 0.5f, y = ly * Wl - 0.5f;
      float x0f = floorf(x), y0f = floorf(y);
      float fx = x - x0f, fy = y - y0f;
      int x0 = (int)x0f, y0 = (int)y0f;
      float v0 = 0.f, v1 = 0.f, v2 = 0.f, v3 = 0.f;
      #pragma unroll
      for (int ty = 0; ty < 2; ++ty) {
        int yi = y0 + ty;
        float wy = ty ? fy : (1.f - fy);
        if (yi < 0 || yi >= Wl) continue;
        #pragma unroll
        for (int txi = 0; txi < 2; ++txi) {
          int xi = x0 + txi;
          float wx = txi ? fx : (1.f - fx);
          if (xi < 0 || xi >= Wl) continue;
          unsigned long long vv =
              *(const unsigned long long*)&Vb[(size_t)(st + yi*Wl + xi) * 32];
          float ww = wy * wx;
          v0 += ww * __uint_as_float((unsigned)(vv) << 16);
          v1 += ww * __uint_as_float((unsigned)(vv) & 0xffff0000u);
          v2 += ww * __uint_as_float((unsigned)(vv >> 32) << 16);
          v3 += ww * __uint_as_float((unsigned)(vv >> 32) & 0xffff0000u);
        }
      }
      float aw = s_aw[q][h*16 + l*4 + p];
      a0 += aw * v0; a1 += aw * v1; a2 += aw * v2; a3 += aw * v3;
    }
  }
  short4 sv = make_short4(f2bf_s(a0), f2bf_s(a1), f2bf_s(a2), f2bf_s(a3));
  *(short4*)&out[(size_t)row*D_ + h*DH + dq*4] = sv;
}

// ================================================================ launch
extern "C" void kernel_launch(void* const* d_in, const int* in_sizes, int n_in,
                              void* d_out, int out_size, void* d_ws, size_t ws_size,
                              hipStream_t stream)
{
  const float* tgt    = (const float*)d_in[0];
  const float* memory = (const float*)d_in[1];
  const float* qpos   = (const float*)d_in[2];
  const float* boxes  = (const float*)d_in[3];
  const float* refp   = (const float*)d_in[4];
  const float* wq = (const float*)d_in[5];   const float* bq = (const float*)d_in[6];
  const float* wk = (const float*)d_in[7];   const float* bk = (const float*)d_in[8];
  const float* wv = (const float*)d_in[9];   const float* bv = (const float*)d_in[10];
  const float* sa_wo = (const float*)d_in[11]; const float* sa_bo = (const float*)d_in[12];
  const float* n1g = (const float*)d_in[13]; const float* n1b = (const float*)d_in[14];
  const float* off_w = (const float*)d_in[15]; const float* off_b = (const float*)d_in[16];
  const float* aw_w  = (const float*)d_in[17]; const float* aw_b  = (const float*)d_in[18];
  const float* val_w = (const float*)d_in[19]; const float* val_b = (const float*)d_in[20];
  const float* co_w  = (const float*)d_in[21]; const float* co_b  = (const float*)d_in[22];
  const float* n2g = (const float*)d_in[23]; const float* n2b = (const float*)d_in[24];
  const float* ff1_w = (const float*)d_in[25]; const float* ff1_b = (const float*)d_in[26];
  const float* ff2_w = (const float*)d_in[27]; const float* ff2_b = (const float*)d_in[28];
  const float* n3g = (const float*)d_in[29]; const float* n3b = (const float*)d_in[30];

  char* ws = (char*)d_ws;
  size_t NE = (size_t)NROWS * D_;
  __hip_bfloat16* Vv = (__hip_bfloat16*)ws;     // value bf16 [b][h][pix][32]
  __hip_bfloat16* FFM = (__hip_bfloat16*)ws;    // ffn hidden bf16 overlays (Vv dead)
  size_t p = (size_t)B_ * S_ * D_ * sizeof(__hip_bfloat16);
  float* A  = (float*)(ws + p); p += NE*4;      // rope out (bf16)
  float* Qb = (float*)(ws + p); p += NE*4;      // q bf16 / off fp32
  float* Kb = (float*)(ws + p); p += NE*4;      // k bf16 / aw fp32; Wt in tail
  float* Vh = (float*)(ws + p); p += NE*4;      // Vt bf16 (attn V transposed)
  float* S1 = (float*)(ws + p); p += NE*4;      // attn out / sampled (bf16)
  float* S2 = (float*)(ws + p); p += NE*4;      // bf16 aux (T1+qpos) / bf16 T1
  float* T1 = (float*)(ws + p); p += NE*4;      // tgt1 / tgt2
  short* Wt = (short*)((char*)Kb + NE*2);       // 3.08 MB in free tail of Kb
  float* out = (float*)d_out;
  (void)ws_size; (void)in_sizes; (void)n_in; (void)out_size;

  const short* qk_t  = Wt;                 // [512][256]
  const short* wv_t  = Wt + 131072;
  const short* sa_t  = Wt + 196608;
  const short* offaw_t = Wt + 262144;      // [384][256]
  const short* val_t = Wt + 360448;
  const short* co_t  = Wt + 425984;
  const short* ff1_t = Wt + 491520;
  const short* ff2_t = Wt + 1015808;

  wtrans_kernel<<<1504, 256, 0, stream>>>(wq, wk, wv, sa_wo, off_w, val_w,
                                          co_w, aw_w, ff1_w, ff2_w, Wt);

  // self-attention branch prologue
  rope_kernel<<<NROWS, 128, 0, stream>>>(tgt, qpos, boxes, (__hip_bfloat16*)A);
  mgemm_kernel<32,256,true,false,false,3,0><<<dim3(225,2), 256, 0, stream>>>(
      A, nullptr, qk_t, bq, bk, Qb, Kb, NROWS, 512, nullptr, nullptr, nullptr);
  mgemm_kernel<32,256,false,false,false,2,0><<<dim3(225,1), 256, 0, stream>>>(
      tgt, nullptr, wv_t, bv, nullptr, Vh, nullptr, NROWS, 256, nullptr, nullptr, nullptr);

  // FUSED: value GEMM (blocks 0..1087) + attention (blocks 1088..1319)
  vgemm_attn_kernel<<<1320, 512, 0, stream>>>(
      memory, val_t, val_b, (short*)Vv,
      (const __hip_bfloat16*)Qb, (const __hip_bfloat16*)Kb,
      (const __hip_bfloat16*)Vh, (__hip_bfloat16*)S1);

  // sa projection + residual + LN1 fused -> T1 fp32, plus bf16 (T1+qpos) -> S2
  mgemm_kernel<32,256,true,false,false,5,1><<<dim3(225,1), 256, 0, stream>>>(
      S1, qpos, sa_t, sa_bo, nullptr, T1, S2, NROWS, 256, tgt, n1g, n1b);

  // cross-attention branch
  mgemm_kernel<32,256,true,false,false,4,0><<<dim3(225,2), 256, 0, stream>>>(
      S2, nullptr, offaw_t, off_b, aw_b, Qb, Kb, NROWS, 384, nullptr, nullptr, nullptr);
  sample4_kernel<<<NROWS/4, 256, 0, stream>>>(Vv, Qb, Kb, refp, (short*)S1);
  mgemm_kernel<32,256,true,false,false,5,2><<<dim3(225,1), 256, 0, stream>>>(
      S1, nullptr, co_t, co_b, nullptr, T1, S2, NROWS, 256, T1, n2g, n2b);

  // ffn (split): ff1 consumes bf16 T1 aux, BM=64
  mgemm_kernel<64,256,true,false,true,1,0><<<dim3(113,8), 256, 0, stream>>>(
      S2, nullptr, ff1_t, ff1_b, nullptr, FFM, nullptr, NROWS, FF_, nullptr, nullptr, nullptr);
  mgemm_kernel<32,2048,true,false,false,5,0><<<dim3(225,1), 256, 0, stream>>>(
      FFM, nullptr, ff2_t, ff2_b, nullptr, out, nullptr, NROWS, 256, T1, n3g, n3b);
}

// Round 21
// 389.270 us; speedup vs baseline: 1.0132x; 1.0132x over previous
//
#include <hip/hip_runtime.h>
#include <hip/hip_bf16.h>
#include <math.h>

#define B_ 8
#define N_ 900
#define D_ 256
#define S_ 21760
#define H_ 8
#define DH 32
#define FF_ 2048
#define NROWS (B_*N_)   // 7200

typedef __attribute__((ext_vector_type(8))) short bf16x8;
typedef __attribute__((ext_vector_type(4))) float f32x4;

union BU { bf16x8 v; short s[8]; unsigned long long u[2]; };

static __device__ inline short f2bf_s(float x) {
  __hip_bfloat16 h = __float2bfloat16(x);
  return *reinterpret_cast<short*>(&h);
}

__device__ __forceinline__ void gload_lds16(const float* g, float* lds) {
  __builtin_amdgcn_global_load_lds(
      (const __attribute__((address_space(1))) void*)g,
      (__attribute__((address_space(3))) void*)lds, 16, 0, 0);
}

// ---------------------------------------------------------------- RoPE (bf16 out)
__global__ __launch_bounds__(128) void rope_kernel(
    const float* __restrict__ tgt, const float* __restrict__ qpos,
    const float* __restrict__ boxes, __hip_bfloat16* __restrict__ out)
{
  int row = blockIdx.x;
  int tid = threadIdx.x;
  const float* x = tgt  + (size_t)row * D_;
  const float* p = qpos + (size_t)row * D_;
  float a0 = x[2*tid]   + p[2*tid];
  float a1 = x[2*tid+1] + p[2*tid+1];
  float o0 = a0, o1 = a1;
  if (tid < 126) {
    int band = tid / 42;
    int fi   = tid - band * 42;
    float freq = powf(10000.0f, -(float)fi / 42.0f);
    float cx = boxes[(size_t)row*4 + 0];
    float cy = boxes[(size_t)row*4 + 1];
    float v  = (band == 0) ? cx : (band == 1 ? cy : cx * cy);
    if (band == 2) freq *= 0.1f;
    float ang = v * freq;
    float c = cosf(ang), s = sinf(ang);
    o0 = a0 * c - a1 * s;
    o1 = a1 * c + a0 * s;
  }
  short2 sv = make_short2(f2bf_s(o0), f2bf_s(o1));
  *(short2*)&out[(size_t)row*D_ + 2*tid] = sv;
}

// ---------------------------------------------------------------- weight transpose+convert
// Layout (elems): qk 0 (wq@0, wk@65536), wv 131072, sa 196608,
// off 262144, aw 327680, val 360448, co 425984, ff1 491520, ff2 1015808.
__global__ __launch_bounds__(256) void wtrans_kernel(
    const float* __restrict__ wq, const float* __restrict__ wk,
    const float* __restrict__ wv, const float* __restrict__ sa_wo,
    const float* __restrict__ offw, const float* __restrict__ valw,
    const float* __restrict__ cow, const float* __restrict__ aww,
    const float* __restrict__ ff1w, const float* __restrict__ ff2w,
    short* __restrict__ Wt)
{
  int bid = blockIdx.x;
  const float* W; short* out; int K, N, tile;
  if (bid < 448) {
    int wi = bid >> 6; tile = bid & 63; K = 256; N = 256;
    const float* tab[7] = {wq, wk, wv, sa_wo, offw, valw, cow};
    const int   off[7]  = {0, 65536, 131072, 196608, 262144, 360448, 425984};
    W = tab[wi]; out = Wt + off[wi];
  } else if (bid < 480) {
    tile = bid - 448; K = 256; N = 128; W = aww; out = Wt + 327680;
  } else if (bid < 992) {
    tile = bid - 480; K = 256; N = 2048; W = ff1w; out = Wt + 491520;
  } else {
    tile = bid - 992; K = 2048; N = 256; W = ff2w; out = Wt + 1015808;
  }
  int ntn = N >> 5;
  int tk = tile / ntn, tn = tile - tk * ntn;
  __shared__ float t[32][33];
  int c = threadIdx.x & 31, rr = threadIdx.x >> 5;
  #pragma unroll
  for (int i = 0; i < 4; ++i)
    t[rr + i*8][c] = W[(size_t)(tk*32 + rr + i*8) * N + tn*32 + c];
  __syncthreads();
  #pragma unroll
  for (int i = 0; i < 4; ++i)
    out[(size_t)(tn*32 + rr + i*8) * K + tk*32 + c] = f2bf_s(t[c][rr + i*8]);
}

// ---------------------------------------------------------------- MFMA GEMM (K-strip)
// OUTMODE: 0 fp32 [M][N]; 1 bf16 [M][N]; 2 bf16 attn-V transpose;
//          3 dual bf16; 4 dual fp32; 5 fused residual-add + LayerNorm.
// AUX (OUTMODE 5 only): 0 none; 1 also write bf16 (LN_out + A2p row) to Cp2;
//                       2 also write bf16 LN_out to Cp2.
template<int BM, int KK, bool ABF16, bool A2ADD, bool RELU, int OUTMODE, int AUX>
__global__ __launch_bounds__(256) void mgemm_kernel(
    const void* __restrict__ Ap, const float* __restrict__ A2p,
    const short* __restrict__ Wt,
    const float* __restrict__ bias, const float* __restrict__ bias2,
    void* __restrict__ Cp, void* __restrict__ Cp2, int M, int N,
    const float* __restrict__ Xres, const float* __restrict__ lng,
    const float* __restrict__ lnb)
{
  constexpr int MS = BM / 16;
  constexpr bool SWAP = (OUTMODE != 2);
  __shared__ short As[BM * 256];
  int tid = threadIdx.x;
  int w = tid >> 6, lane = tid & 63;
  int g = lane >> 4, r = lane & 15;
  int m0 = blockIdx.x * BM;
  int nw = blockIdx.y * 256 + w * 64;
  bool active = nw < N;

  f32x4 acc[MS][4];
  #pragma unroll
  for (int i = 0; i < MS; ++i)
    #pragma unroll
    for (int j = 0; j < 4; ++j) acc[i][j] = (f32x4){0.f,0.f,0.f,0.f};

  for (int kb = 0; kb < KK; kb += 256) {
    if (KK > 256 && kb) __syncthreads();
    #pragma unroll
    for (int i = 0; i < BM/8; ++i) {
      int u = i*256 + tid;
      int row = u >> 5, c8 = u & 31;
      BU pk;
      if (ABF16) {
        pk.v = *(const bf16x8*)((const short*)Ap + (size_t)(m0+row)*KK + kb + c8*8);
      } else {
        const float* ap = (const float*)Ap + (size_t)(m0+row)*KK + kb + c8*8;
        float4 a0 = *(const float4*)ap;
        float4 a1 = *(const float4*)(ap + 4);
        if (A2ADD) {
          const float* a2 = A2p + (size_t)(m0+row)*KK + kb + c8*8;
          float4 b0 = *(const float4*)a2;
          float4 b1 = *(const float4*)(a2 + 4);
          a0.x += b0.x; a0.y += b0.y; a0.z += b0.z; a0.w += b0.w;
          a1.x += b1.x; a1.y += b1.y; a1.z += b1.z; a1.w += b1.w;
        }
        pk.s[0]=f2bf_s(a0.x); pk.s[1]=f2bf_s(a0.y); pk.s[2]=f2bf_s(a0.z); pk.s[3]=f2bf_s(a0.w);
        pk.s[4]=f2bf_s(a1.x); pk.s[5]=f2bf_s(a1.y); pk.s[6]=f2bf_s(a1.z); pk.s[7]=f2bf_s(a1.w);
      }
      int col = (c8*8) ^ ((row & 7) << 3);
      *(bf16x8*)&As[row*256 + col] = pk.v;
    }
    __syncthreads();
    if (active) {
      #pragma unroll
      for (int kk = 0; kk < 8; ++kk) {
        BU bfr[4];
        #pragma unroll
        for (int ns = 0; ns < 4; ++ns) {
          const short* wp = Wt + (size_t)(nw + ns*16 + r)*KK + kb + kk*32;
          bfr[ns].u[0] = *(const unsigned long long*)(wp + 4*g);
          bfr[ns].u[1] = *(const unsigned long long*)(wp + 16 + 4*g);
        }
        #pragma unroll
        for (int ms = 0; ms < MS; ++ms) {
          int row = ms*16 + r;
          int c0 = (kk*32 + g*4)      ^ ((r & 7) << 3);
          int c1 = (kk*32 + 16 + g*4) ^ ((r & 7) << 3);
          BU af;
          af.u[0] = *(const unsigned long long*)&As[row*256 + c0];
          af.u[1] = *(const unsigned long long*)&As[row*256 + c1];
          #pragma unroll
          for (int ns = 0; ns < 4; ++ns) {
            if (SWAP)
              acc[ms][ns] = __builtin_amdgcn_mfma_f32_16x16x32_bf16(
                  bfr[ns].v, af.v, acc[ms][ns], 0, 0, 0);
            else
              acc[ms][ns] = __builtin_amdgcn_mfma_f32_16x16x32_bf16(
                  af.v, bfr[ns].v, acc[ms][ns], 0, 0, 0);
          }
        }
      }
    }
  }

  if (OUTMODE == 5) {
    float vv[MS][16];
    float ps[MS], pq[MS];
    #pragma unroll
    for (int ms = 0; ms < MS; ++ms) {
      ps[ms] = 0.f; pq[ms] = 0.f;
      int m = m0 + ms*16 + r;
      #pragma unroll
      for (int ns = 0; ns < 4; ++ns) {
        int n0 = nw + ns*16 + g*4;
        float4 b4 = *(const float4*)&bias[n0];
        float4 x4 = *(const float4*)&Xres[(size_t)m*256 + n0];
        #pragma unroll
        for (int j = 0; j < 4; ++j) {
          float v = acc[ms][ns][j] + ((const float*)&b4)[j] + ((const float*)&x4)[j];
          vv[ms][ns*4 + j] = v;
          ps[ms] += v; pq[ms] += v*v;
        }
      }
      ps[ms] += __shfl_xor(ps[ms], 16); ps[ms] += __shfl_xor(ps[ms], 32);
      pq[ms] += __shfl_xor(pq[ms], 16); pq[ms] += __shfl_xor(pq[ms], 32);
    }
    __syncthreads();
    float* red = (float*)As;
    if (g == 0) {
      #pragma unroll
      for (int ms = 0; ms < MS; ++ms) {
        red[(ms*16 + r)*8 + w]     = ps[ms];
        red[(ms*16 + r)*8 + 4 + w] = pq[ms];
      }
    }
    __syncthreads();
    #pragma unroll
    for (int ms = 0; ms < MS; ++ms) {
      int rowi = ms*16 + r;
      float ts = red[rowi*8+0]+red[rowi*8+1]+red[rowi*8+2]+red[rowi*8+3];
      float tq = red[rowi*8+4]+red[rowi*8+5]+red[rowi*8+6]+red[rowi*8+7];
      float mu = ts * (1.0f/256.0f);
      float var = tq * (1.0f/256.0f) - mu*mu;
      float rs = rsqrtf(fmaxf(var, 0.f) + 1e-5f);
      int m = m0 + ms*16 + r;
      #pragma unroll
      for (int ns = 0; ns < 4; ++ns) {
        int n0 = nw + ns*16 + g*4;
        float4 g4 = *(const float4*)&lng[n0];
        float4 be = *(const float4*)&lnb[n0];
        float4 ov;
        ov.x = (vv[ms][ns*4+0] - mu)*rs*g4.x + be.x;
        ov.y = (vv[ms][ns*4+1] - mu)*rs*g4.y + be.y;
        ov.z = (vv[ms][ns*4+2] - mu)*rs*g4.z + be.z;
        ov.w = (vv[ms][ns*4+3] - mu)*rs*g4.w + be.w;
        *(float4*)&((float*)Cp)[(size_t)m*256 + n0] = ov;
        if (AUX == 1) {
          float4 q4 = *(const float4*)&A2p[(size_t)m*256 + n0];
          short4 sv = make_short4(
              f2bf_s(ov.x + q4.x), f2bf_s(ov.y + q4.y),
              f2bf_s(ov.z + q4.z), f2bf_s(ov.w + q4.w));
          *(short4*)&((short*)Cp2)[(size_t)m*256 + n0] = sv;
        } else if (AUX == 2) {
          short4 sv = make_short4(
              f2bf_s(ov.x), f2bf_s(ov.y), f2bf_s(ov.z), f2bf_s(ov.w));
          *(short4*)&((short*)Cp2)[(size_t)m*256 + n0] = sv;
        }
      }
    }
    return;
  }

  if (!active) return;

  #pragma unroll
  for (int ms = 0; ms < MS; ++ms) {
    #pragma unroll
    for (int ns = 0; ns < 4; ++ns) {
      if (SWAP) {
        int n0 = nw + ns*16 + g*4;
        int m  = m0 + ms*16 + r;
        float4 b4;
        if (OUTMODE == 3 || OUTMODE == 4)
          b4 = (n0 < 256) ? *(const float4*)&bias[n0]
                          : *(const float4*)&bias2[n0 - 256];
        else
          b4 = *(const float4*)&bias[n0];
        float v0 = acc[ms][ns][0] + b4.x;
        float v1 = acc[ms][ns][1] + b4.y;
        float v2 = acc[ms][ns][2] + b4.z;
        float v3 = acc[ms][ns][3] + b4.w;
        if (RELU) {
          v0 = fmaxf(v0, 0.f); v1 = fmaxf(v1, 0.f);
          v2 = fmaxf(v2, 0.f); v3 = fmaxf(v3, 0.f);
        }
        if (OUTMODE == 0) {
          *(float4*)&((float*)Cp)[(size_t)m*N + n0] = make_float4(v0,v1,v2,v3);
        } else if (OUTMODE == 1) {
          short4 sv = make_short4(f2bf_s(v0), f2bf_s(v1), f2bf_s(v2), f2bf_s(v3));
          *(short4*)&((short*)Cp)[(size_t)m*N + n0] = sv;
        } else if (OUTMODE == 3) {
          short4 sv = make_short4(f2bf_s(v0), f2bf_s(v1), f2bf_s(v2), f2bf_s(v3));
          if (n0 < 256) *(short4*)&((short*)Cp )[(size_t)m*256 + n0]       = sv;
          else          *(short4*)&((short*)Cp2)[(size_t)m*256 + (n0-256)] = sv;
        } else {  // OUTMODE 4
          float4 fv = make_float4(v0,v1,v2,v3);
          if (n0 < 256) *(float4*)&((float*)Cp )[(size_t)m*256 + n0]       = fv;
          else          *(float4*)&((float*)Cp2)[(size_t)m*128 + (n0-256)] = fv;
        }
      } else {  // OUTMODE 2: attn-V transpose
        int n = nw + ns*16 + r;
        float bsc = bias[n];
        int hh = n >> 5, dd = n & 31;
        int mb = m0 + ms*16 + g*4;
        short4 sv = make_short4(
            f2bf_s(acc[ms][ns][0] + bsc), f2bf_s(acc[ms][ns][1] + bsc),
            f2bf_s(acc[ms][ns][2] + bsc), f2bf_s(acc[ms][ns][3] + bsc));
        int bb = mb / N_, bbe = (mb + 3) / N_;
        if (bb == bbe) {
          int nn = mb - bb * N_;
          *(short4*)&((short*)Cp)[((size_t)((bb*H_ + hh)*DH + dd))*N_ + nn] = sv;
        } else {
          const short* sp = (const short*)&sv;
          #pragma unroll
          for (int j = 0; j < 4; ++j) {
            int m = mb + j;
            int b2 = m / N_, nn = m - b2 * N_;
            ((short*)Cp)[((size_t)((b2*H_ + hh)*DH + dd))*N_ + nn] = sp[j];
          }
        }
      }
    }
  }
}

// ---------------------------------------------------------------- value GEMM: persistent async-DMA pipeline
// 8 waves x 32 cols (wreg register-resident); 2 chunks per barrier, vmcnt(4).
__global__ __launch_bounds__(512) void vgemm_kernel(
    const float* __restrict__ Ap, const short* __restrict__ Wt,
    const float* __restrict__ bias, short* __restrict__ Cp)
{
  __shared__ float buf[8][1024];
  __shared__ float dump[1024];
  int tid = threadIdx.x;
  int w = tid >> 6, l = tid & 63;
  int g = l >> 4, r = l & 15;
  int nw = w * 32;

  BU wreg[2][8];
  #pragma unroll
  for (int ns = 0; ns < 2; ++ns) {
    const short* wp = Wt + (size_t)(nw + ns*16 + r) * 256;
    #pragma unroll
    for (int kk = 0; kk < 8; ++kk) {
      wreg[ns][kk].u[0] = *(const unsigned long long*)(wp + kk*32 + 4*g);
      wreg[ns][kk].u[1] = *(const unsigned long long*)(wp + kk*32 + 16 + 4*g);
    }
  }
  float4 bs4[2];
  #pragma unroll
  for (int ns = 0; ns < 2; ++ns) bs4[ns] = *(const float4*)&bias[nw + ns*16 + g*4];

  bool stager = (w < 4);
  int srow = (w & 3)*8 + (l >> 3);
  int schunk = (l & 7) ^ (srow & 7);
  const float* gbase = Ap + ((size_t)blockIdx.x*160 + srow) * 256 + schunk*4;

  if (stager) {
    #pragma unroll
    for (int t = 0; t < 4; ++t)
      gload_lds16(gbase + (t>>3)*8192 + (t&7)*32, &buf[t][(w & 3)*256]);
  }

  f32x4 acc[2][2];
  #pragma unroll
  for (int i = 0; i < 2; ++i)
    #pragma unroll
    for (int j = 0; j < 2; ++j) acc[i][j] = (f32x4){0.f,0.f,0.f,0.f};

  int bb = blockIdx.x / 136;
  int pixblk = (blockIdx.x % 136) * 160;

  for (int s = 0; s < 5; ++s) {
    #pragma unroll
    for (int cp = 0; cp < 4; ++cp) {
      int c = cp*2;
      int t = s*8 + c;
      if (stager) {
        int tn0 = t + 4, tn1 = t + 5;
        if (tn0 < 40) gload_lds16(gbase + (tn0>>3)*8192 + (tn0&7)*32,
                                  &buf[(c+4)&7][(w & 3)*256]);
        else          gload_lds16(gbase, &dump[(w & 3)*256]);
        if (tn1 < 40) gload_lds16(gbase + (tn1>>3)*8192 + (tn1&7)*32,
                                  &buf[(c+5)&7][(w & 3)*256]);
        else          gload_lds16(gbase, &dump[(w & 3)*256]);
        asm volatile("s_waitcnt vmcnt(4)" ::: "memory");
      }
      __builtin_amdgcn_s_barrier();
      #pragma unroll
      for (int cc = 0; cc < 2; ++cc) {
        int ci = c + cc;
        const float* bp = &buf[ci][0];
        #pragma unroll
        for (int ms = 0; ms < 2; ++ms) {
          int row = ms*16 + r;
          const float* rp = bp + row*32;
          float4 f0 = *(const float4*)&rp[((g    ) ^ (row & 7)) * 4];
          float4 f1 = *(const float4*)&rp[((g + 4) ^ (row & 7)) * 4];
          BU af;
          af.s[0]=f2bf_s(f0.x); af.s[1]=f2bf_s(f0.y); af.s[2]=f2bf_s(f0.z); af.s[3]=f2bf_s(f0.w);
          af.s[4]=f2bf_s(f1.x); af.s[5]=f2bf_s(f1.y); af.s[6]=f2bf_s(f1.z); af.s[7]=f2bf_s(f1.w);
          #pragma unroll
          for (int ns = 0; ns < 2; ++ns)
            acc[ms][ns] = __builtin_amdgcn_mfma_f32_16x16x32_bf16(
                wreg[ns][ci].v, af.v, acc[ms][ns], 0, 0, 0);
        }
      }
    }
    int pix0 = pixblk + s*32;
    #pragma unroll
    for (int ms = 0; ms < 2; ++ms) {
      #pragma unroll
      for (int ns = 0; ns < 2; ++ns) {
        int pix = pix0 + ms*16 + r;
        int n0  = nw + ns*16 + g*4;
        int hh = n0 >> 5, dd = n0 & 31;
        short4 sv = make_short4(
            f2bf_s(acc[ms][ns][0] + bs4[ns].x),
            f2bf_s(acc[ms][ns][1] + bs4[ns].y),
            f2bf_s(acc[ms][ns][2] + bs4[ns].z),
            f2bf_s(acc[ms][ns][3] + bs4[ns].w));
        *(short4*)&Cp[((size_t)(bb*H_ + hh)*S_ + pix)*32 + dd] = sv;
        acc[ms][ns] = (f32x4){0.f,0.f,0.f,0.f};
      }
    }
  }
}

// ---------------------------------------------------------------- MFMA flash attention (32 q-rows/wave, bf16 out)
__global__ __launch_bounds__(64) void mfma_attn_kernel(
    const __hip_bfloat16* __restrict__ Q,
    const __hip_bfloat16* __restrict__ K,
    const __hip_bfloat16* __restrict__ Vt,
    __hip_bfloat16* __restrict__ O)
{
  const int NQT = 29;
  int wid = blockIdx.x;
  int qt = wid % NQT, bh = wid / NQT;
  int b = bh >> 3, h = bh & 7;
  int lane = threadIdx.x;
  int g = lane >> 4, r = lane & 15;
  int q0 = qt * 32;
  const float scale = 0.17677669529663687f;

  union U { bf16x8 v; short s[8]; unsigned long long u64[2]; };

  U qf[2];
  #pragma unroll
  for (int qq = 0; qq < 2; ++qq) {
    int qrow = min(q0 + qq*16 + r, N_ - 1);
    const __hip_bfloat16* qp = Q + ((size_t)(b*N_ + qrow))*D_ + h*DH;
    qf[qq].u64[0] = *(const unsigned long long*)(qp + 4*g);
    qf[qq].u64[1] = *(const unsigned long long*)(qp + 16 + 4*g);
  }

  f32x4 oaccA[2], oaccB[2];
  #pragma unroll
  for (int qq = 0; qq < 2; ++qq) {
    oaccA[qq] = (f32x4){0.f,0.f,0.f,0.f};
    oaccB[qq] = (f32x4){0.f,0.f,0.f,0.f};
  }
  float m0v = -1e30f, m1v = -1e30f, l0v = 0.f, l1v = 0.f;
  const f32x4 zero = {0.f,0.f,0.f,0.f};

  const __hip_bfloat16* vbase0 = Vt + (size_t)(bh*DH + r) * N_;
  const __hip_bfloat16* vbase1 = Vt + (size_t)(bh*DH + 16 + r) * N_;

  for (int kt = 0; kt < N_; kt += 32) {
    U kf0, kf1;
    {
      int kr0 = min(kt + r, N_ - 1);
      int kr1 = min(kt + 16 + r, N_ - 1);
      const __hip_bfloat16* kp0 = K + ((size_t)(b*N_ + kr0))*D_ + h*DH;
      const __hip_bfloat16* kp1 = K + ((size_t)(b*N_ + kr1))*D_ + h*DH;
      kf0.u64[0] = *(const unsigned long long*)(kp0 + 4*g);
      kf0.u64[1] = *(const unsigned long long*)(kp0 + 16 + 4*g);
      kf1.u64[0] = *(const unsigned long long*)(kp1 + 4*g);
      kf1.u64[1] = *(const unsigned long long*)(kp1 + 16 + 4*g);
    }
    U vf0, vf1;
    vf0.u64[0] = *(const unsigned long long*)(vbase0 + kt + 4*g);
    vf0.u64[1] = *(const unsigned long long*)(vbase0 + kt + 16 + 4*g);
    vf1.u64[0] = *(const unsigned long long*)(vbase1 + kt + 4*g);
    vf1.u64[1] = *(const unsigned long long*)(vbase1 + kt + 16 + 4*g);

    #pragma unroll
    for (int qq = 0; qq < 2; ++qq) {
      f32x4 s0 = __builtin_amdgcn_mfma_f32_16x16x32_bf16(kf0.v, qf[qq].v, zero, 0, 0, 0);
      f32x4 s1 = __builtin_amdgcn_mfma_f32_16x16x32_bf16(kf1.v, qf[qq].v, zero, 0, 0, 0);
      float m = qq ? m1v : m0v;
      float lv = qq ? l1v : l0v;

      float sc[8];
      #pragma unroll
      for (int j = 0; j < 4; ++j) {
        sc[j]   = (kt + 4*g + j      < N_) ? s0[j] * scale : -1e30f;
        sc[4+j] = (kt + 16 + 4*g + j < N_) ? s1[j] * scale : -1e30f;
      }
      float mx = sc[0];
      #pragma unroll
      for (int j = 1; j < 8; ++j) mx = fmaxf(mx, sc[j]);
      mx = fmaxf(mx, __shfl_xor(mx, 16));
      mx = fmaxf(mx, __shfl_xor(mx, 32));

      float mnew = fmaxf(m, mx);
      float corr = __expf(m - mnew);
      float p[8], ps = 0.f;
      #pragma unroll
      for (int j = 0; j < 8; ++j) { p[j] = __expf(sc[j] - mnew); ps += p[j]; }
      ps += __shfl_xor(ps, 16);
      ps += __shfl_xor(ps, 32);
      lv = lv * corr + ps;
      if (qq) { m1v = mnew; l1v = lv; } else { m0v = mnew; l0v = lv; }
      #pragma unroll
      for (int j = 0; j < 4; ++j) { oaccA[qq][j] *= corr; oaccB[qq][j] *= corr; }

      U pf;
      #pragma unroll
      for (int j = 0; j < 8; ++j) pf.s[j] = f2bf_s(p[j]);

      oaccA[qq] = __builtin_amdgcn_mfma_f32_16x16x32_bf16(vf0.v, pf.v, oaccA[qq], 0, 0, 0);
      oaccB[qq] = __builtin_amdgcn_mfma_f32_16x16x32_bf16(vf1.v, pf.v, oaccB[qq], 0, 0, 0);
    }
  }

  #pragma unroll
  for (int qq = 0; qq < 2; ++qq) {
    int qrow = q0 + qq*16 + r;
    if (qrow < N_) {
      float inv = 1.0f / (qq ? l1v : l0v);
      short* op = (short*)(O + ((size_t)(b*N_ + qrow))*D_ + h*DH);
      short4 sA = make_short4(
          f2bf_s(oaccA[qq][0]*inv), f2bf_s(oaccA[qq][1]*inv),
          f2bf_s(oaccA[qq][2]*inv), f2bf_s(oaccA[qq][3]*inv));
      short4 sB = make_short4(
          f2bf_s(oaccB[qq][0]*inv), f2bf_s(oaccB[qq][1]*inv),
          f2bf_s(oaccB[qq][2]*inv), f2bf_s(oaccB[qq][3]*inv));
      *(short4*)&op[4*g]      = sA;
      *(short4*)&op[16 + 4*g] = sB;
    }
  }
}

// ---------------------------------------------------------------- deformable sampling (4 rows/block, d-quad gathers, bf16 out)
// V layout: [b][h][pix][32]  (pixel stride 64 B)
__global__ __launch_bounds__(256) void sample4_kernel(
    const __hip_bfloat16* __restrict__ V, const float* __restrict__ offp,
    const float* __restrict__ awl, const float* __restrict__ refp,
    short* __restrict__ out)
{
  int tid = threadIdx.x;
  int q = tid >> 6, t = tid & 63;
  int row = blockIdx.x * 4 + q;
  int b = row / N_;
  __shared__ float s_aw[4][128];
  __shared__ float s_loc[4][256];
  #pragma unroll
  for (int i = 0; i < 2; ++i)
    s_aw[q][t + i*64] = awl[(size_t)row*128 + t + i*64];
  {
    const float norms[4] = {128.f, 64.f, 32.f, 16.f};
    #pragma unroll
    for (int i = 0; i < 4; ++i) {
      int e = t + i*64;
      int rem = e & 31, li = rem >> 3, ax = rem & 1;
      s_loc[q][e] = refp[((size_t)row*4 + li)*2 + ax]
                  + offp[(size_t)row*256 + e] / norms[li];
    }
  }
  __syncthreads();
  if (t < 8) {
    float mx = -1e30f;
    for (int j = 0; j < 16; ++j) mx = fmaxf(mx, s_aw[q][t*16+j]);
    float sum = 0.f;
    for (int j = 0; j < 16; ++j) sum += __expf(s_aw[q][t*16+j] - mx);
    float inv = 1.0f / sum;
    for (int j = 0; j < 16; ++j)
      s_aw[q][t*16+j] = __expf(s_aw[q][t*16+j] - mx) * inv;
  }
  __syncthreads();
  int h = t >> 3, dq = t & 7;
  const int dims[4]   = {128, 64, 32, 16};
  const int starts[4] = {0, 16384, 20480, 21504};
  const __hip_bfloat16* Vb = V + ((size_t)(b*H_ + h) * S_) * 32 + dq*4;
  float a0 = 0.f, a1 = 0.f, a2 = 0.f, a3 = 0.f;
  #pragma unroll
  for (int l = 0; l < 4; ++l) {
    int Wl = dims[l], st = starts[l];
    #pragma unroll
    for (int p = 0; p < 4; ++p) {
      float lx = s_loc[q][h*32 + l*8 + p*2 + 0];
      float ly = s_loc[q][h*32 + l*8 + p*2 + 1];
      float x = lx * Wl - 0.5f, y = ly * Wl - 0.5f;
      float x0f = floorf(x), y0f = floorf(y);
      float fx = x - x0f, fy = y - y0f;
      int x0 = (int)x0f, y0 = (int)y0f;
      float v0 = 0.f, v1 = 0.f, v2 = 0.f, v3 = 0.f;
      #pragma unroll
      for (int ty = 0; ty < 2; ++ty) {
        int yi = y0 + ty;
        float wy = ty ? fy : (1.f - fy);
        if (yi < 0 || yi >= Wl) continue;
        #pragma unroll
        for (int txi = 0; txi < 2; ++txi) {
          int xi = x0 + txi;
          float wx = txi ? fx : (1.f - fx);
          if (xi < 0 || xi >= Wl) continue;
          unsigned long long vv =
              *(const unsigned long long*)&Vb[(size_t)(st + yi*Wl + xi) * 32];
          float ww = wy * wx;
          v0 += ww * __uint_as_float((unsigned)(vv) << 16);
          v1 += ww * __uint_as_float((unsigned)(vv) & 0xffff0000u);
          v2 += ww * __uint_as_float((unsigned)(vv >> 32) << 16);
          v3 += ww * __uint_as_float((unsigned)(vv >> 32) & 0xffff0000u);
        }
      }
      float aw = s_aw[q][h*16 + l*4 + p];
      a0 += aw * v0; a1 += aw * v1; a2 += aw * v2; a3 += aw * v3;
    }
  }
  short4 sv = make_short4(f2bf_s(a0), f2bf_s(a1), f2bf_s(a2), f2bf_s(a3));
  *(short4*)&out[(size_t)row*D_ + h*DH + dq*4] = sv;
}

// ================================================================ launch
extern "C" void kernel_launch(void* const* d_in, const int* in_sizes, int n_in,
                              void* d_out, int out_size, void* d_ws, size_t ws_size,
                              hipStream_t stream)
{
  const float* tgt    = (const float*)d_in[0];
  const float* memory = (const float*)d_in[1];
  const float* qpos   = (const float*)d_in[2];
  const float* boxes  = (const float*)d_in[3];
  const float* refp   = (const float*)d_in[4];
  const float* wq = (const float*)d_in[5];   const float* bq = (const float*)d_in[6];
  const float* wk = (const float*)d_in[7];   const float* bk = (const float*)d_in[8];
  const float* wv = (const float*)d_in[9];   const float* bv = (const float*)d_in[10];
  const float* sa_wo = (const float*)d_in[11]; const float* sa_bo = (const float*)d_in[12];
  const float* n1g = (const float*)d_in[13]; const float* n1b = (const float*)d_in[14];
  const float* off_w = (const float*)d_in[15]; const float* off_b = (const float*)d_in[16];
  const float* aw_w  = (const float*)d_in[17]; const float* aw_b  = (const float*)d_in[18];
  const float* val_w = (const float*)d_in[19]; const float* val_b = (const float*)d_in[20];
  const float* co_w  = (const float*)d_in[21]; const float* co_b  = (const float*)d_in[22];
  const float* n2g = (const float*)d_in[23]; const float* n2b = (const float*)d_in[24];
  const float* ff1_w = (const float*)d_in[25]; const float* ff1_b = (const float*)d_in[26];
  const float* ff2_w = (const float*)d_in[27]; const float* ff2_b = (const float*)d_in[28];
  const float* n3g = (const float*)d_in[29]; const float* n3b = (const float*)d_in[30];

  char* ws = (char*)d_ws;
  size_t NE = (size_t)NROWS * D_;
  __hip_bfloat16* Vv = (__hip_bfloat16*)ws;     // value bf16 [b][h][pix][32]
  __hip_bfloat16* FFM = (__hip_bfloat16*)ws;    // ffn hidden bf16 overlays (Vv dead)
  size_t p = (size_t)B_ * S_ * D_ * sizeof(__hip_bfloat16);
  float* A  = (float*)(ws + p); p += NE*4;      // rope out (bf16)
  float* Qb = (float*)(ws + p); p += NE*4;      // q bf16 / off fp32
  float* Kb = (float*)(ws + p); p += NE*4;      // k bf16 / aw fp32; Wt in tail
  float* Vh = (float*)(ws + p); p += NE*4;      // Vt bf16 (attn V transposed)
  float* S1 = (float*)(ws + p); p += NE*4;      // attn out / sampled (bf16)
  float* S2 = (float*)(ws + p); p += NE*4;      // bf16 aux (T1+qpos) / bf16 T1
  float* T1 = (float*)(ws + p); p += NE*4;      // tgt1 / tgt2
  short* Wt = (short*)((char*)Kb + NE*2);       // 3.08 MB in free tail of Kb
  float* out = (float*)d_out;
  (void)ws_size; (void)in_sizes; (void)n_in; (void)out_size;

  const short* qk_t  = Wt;                 // [512][256]
  const short* wv_t  = Wt + 131072;
  const short* sa_t  = Wt + 196608;
  const short* offaw_t = Wt + 262144;      // [384][256]
  const short* val_t = Wt + 360448;
  const short* co_t  = Wt + 425984;
  const short* ff1_t = Wt + 491520;
  const short* ff2_t = Wt + 1015808;

  wtrans_kernel<<<1504, 256, 0, stream>>>(wq, wk, wv, sa_wo, off_w, val_w,
                                          co_w, aw_w, ff1_w, ff2_w, Wt);

  // self-attention branch
  rope_kernel<<<NROWS, 128, 0, stream>>>(tgt, qpos, boxes, (__hip_bfloat16*)A);
  mgemm_kernel<32,256,true,false,false,3,0><<<dim3(225,2), 256, 0, stream>>>(
      A, nullptr, qk_t, bq, bk, Qb, Kb, NROWS, 512, nullptr, nullptr, nullptr);
  mgemm_kernel<32,256,false,false,false,2,0><<<dim3(225,1), 256, 0, stream>>>(
      tgt, nullptr, wv_t, bv, nullptr, Vh, nullptr, NROWS, 256, nullptr, nullptr, nullptr);
  mfma_attn_kernel<<<29 * B_ * H_, 64, 0, stream>>>(
      (const __hip_bfloat16*)Qb, (const __hip_bfloat16*)Kb,
      (const __hip_bfloat16*)Vh, (__hip_bfloat16*)S1);
  // sa projection + residual + LN1 fused -> T1 fp32, plus bf16 (T1+qpos) -> S2
  mgemm_kernel<32,256,true,false,false,5,1><<<dim3(225,1), 256, 0, stream>>>(
      S1, qpos, sa_t, sa_bo, nullptr, T1, S2, NROWS, 256, tgt, n1g, n1b);

  // cross-attention branch
  vgemm_kernel<<<1088, 512, 0, stream>>>(memory, val_t, val_b, (short*)Vv);
  // off/aw GEMM consumes bf16 (T1+qpos) aux
  mgemm_kernel<32,256,true,false,false,4,0><<<dim3(225,2), 256, 0, stream>>>(
      S2, nullptr, offaw_t, off_b, aw_b, Qb, Kb, NROWS, 384, nullptr, nullptr, nullptr);
  sample4_kernel<<<NROWS/4, 256, 0, stream>>>(Vv, Qb, Kb, refp, (short*)S1);
  // co projection + residual + LN2 fused -> T1 fp32 (in place), plus bf16 T1 -> S2
  mgemm_kernel<32,256,true,false,false,5,2><<<dim3(225,1), 256, 0, stream>>>(
      S1, nullptr, co_t, co_b, nullptr, T1, S2, NROWS, 256, T1, n2g, n2b);

  // ffn (split): ff1 consumes bf16 T1 aux, BM=64 halves W1 re-reads
  mgemm_kernel<64,256,true,false,true,1,0><<<dim3(113,8), 256, 0, stream>>>(
      S2, nullptr, ff1_t, ff1_b, nullptr, FFM, nullptr, NROWS, FF_, nullptr, nullptr, nullptr);
  mgemm_kernel<32,2048,true,false,false,5,0><<<dim3(225,1), 256, 0, stream>>>(
      FFM, nullptr, ff2_t, ff2_b, nullptr, out, nullptr, NROWS, 256, T1, n3g, n3b);
}